// Round 3
// baseline (146.559 us; speedup 1.0000x reference)
//
#include <hip/hip_runtime.h>

// LieSE3: per row [x, y, p_yaw] -> 4x4 SE(3) matrix with z-only rotation.
//
// Closed form (w = 0.1*p, ts = w^2, th = |w|):
//   A  = sin(th)/(th+eps);  Bc = (1-cos th)/(ts+eps);  C = (1-A)/(ts+eps)
//   R00 = R11 = 1 - Bc*ts;  R10 = A*w = -R01;  R22 = 1
//   V00 = V11 = 1 - C*ts;   V10 = Bc*w = -V01
//   t0 = V00*x - Bw*y;  t1 = Bw*x + V00*y;  rows 2,3 = [0,0,1,0],[0,0,0,1]
//
// R5: structural rewrite. Post-mortem of R3/R4 showed the kernel is
// insensitive to LDS bank layout / input vectorization / NT hints -> the
// ~2.5 TB/s ceiling was structural: 7813 short-lived blocks, 2 block-wide
// barriers each, LDS-capped 8 blocks/CU residency, serial per-block
// load->sync->LDS->sync->store chain.
//   - Wave-local exchange instead of LDS: wave owns 64 matrices; store
//     instr k, lane i writes float4 index 256t+64k+i = matrix 16k+(i>>2),
//     row i&3 -- source lane 16k+(i>>2) is IN THIS WAVE. 16 __shfl
//     (ds_bpermute, no barrier) + ~24 cndmask build the rows. Stores stay
//     perfectly contiguous: 4 x 1KB per wave per tile.
//   - Zero LDS, zero __syncthreads: waves fully independent, occupancy no
//     longer LDS-capped, no rendezvous stalls.
//   - Grid-stride persistent waves (2048 blocks, ~4 tiles/wave): amortizes
//     block setup/teardown; tile t+1 loads overlap tile t store drain.
//   - Plain loads/stores (NT was evidence-negative in R4); 3 scalar input
//     loads per lane (stride-12 overlap is absorbed by L1, evidence-neutral).
//   - __fdividef for the 3 divides (rcp-based; absmax tolerance has 1000x
//     headroom over its ~1e-7 rel error).

#define ROTATION_SCALE 0.1f
#define EPS_F 1e-5f

typedef float f4 __attribute__((ext_vector_type(4)));

__global__ __launch_bounds__(256) void lie_se3_kernel(
    const float* __restrict__ uv, f4* __restrict__ out, int B) {
  const int lane = threadIdx.x & 63;
  const int wid = (blockIdx.x * blockDim.x + threadIdx.x) >> 6;  // global wave
  const int nwav = (gridDim.x * blockDim.x) >> 6;
  const int ntile = (B + 63) >> 6;  // 64 matrices per wave-tile
  const int lim4 = 4 * B;           // total output float4s (8e6, fits int)

  for (int t = wid; t < ntile; t += nwav) {
    int m = (t << 6) + lane;  // this lane's matrix
    float x = 0.f, y = 0.f, p = 0.f;
    if (m < B) {
      int g = 3 * m;  // max 6e6, fits int
      x = uv[g + 0];
      y = uv[g + 1];
      p = uv[g + 2];
    }

    float w = p * ROTATION_SCALE;
    float ts = w * w;
    float th = fabsf(w);
    float sn = __sinf(th);
    float cs = __cosf(th);
    float A = __fdividef(sn, th + EPS_F);
    float Bc = __fdividef(1.0f - cs, ts + EPS_F);
    float C = __fdividef(1.0f - A, ts + EPS_F);

    float R00 = 1.0f - Bc * ts;  // == R11
    float Aw = A * w;            // R10 = Aw, R01 = -Aw
    float V00 = 1.0f - C * ts;   // == V11
    float Bw = Bc * w;           // V10 = Bw, V01 = -Bw
    float t0 = V00 * x - Bw * y;
    float t1 = Bw * x + V00 * y;

    const int gbase = t << 8;  // float4 index of this tile's output start
    const int r = lane & 3;    // row this lane stores (in each store instr)
    const bool full = (gbase + 256) <= lim4;  // wave-uniform fast path
#pragma unroll
    for (int k = 0; k < 4; ++k) {
      int src = 16 * k + (lane >> 2);  // lane owning the matrix we store
      float a = __shfl(R00, src, 64);
      float b = __shfl(Aw, src, 64);
      float c0 = __shfl(t0, src, 64);
      float d0 = __shfl(t1, src, 64);
      f4 v;
      v.x = (r == 0) ? a : ((r == 1) ? b : 0.f);
      v.y = (r == 0) ? -b : ((r == 1) ? a : 0.f);
      v.z = (r == 2) ? 1.f : 0.f;
      v.w = (r == 0) ? c0 : ((r == 1) ? d0 : ((r == 3) ? 1.f : 0.f));
      int gi = gbase + 64 * k + lane;  // contiguous 1KB per wave-instr
      if (full || gi < lim4) out[gi] = v;
    }
  }
}

extern "C" void kernel_launch(void* const* d_in, const int* in_sizes, int n_in,
                              void* d_out, int out_size, void* d_ws, size_t ws_size,
                              hipStream_t stream) {
  const float* uv = (const float*)d_in[0];
  f4* out = (f4*)d_out;
  int B = in_sizes[0] / 3;  // 2,000,000
  int grid = (B + 255) / 256;
  if (grid > 2048) grid = 2048;  // persistent waves, grid-stride over tiles
  if (grid < 1) grid = 1;
  lie_se3_kernel<<<grid, 256, 0, stream>>>(uv, out, B);
}